// Round 5
// baseline (105.494 us; speedup 1.0000x reference)
//
#include <hip/hip_runtime.h>
#include <math.h>

// Problem constants: R=4, I=16, N=2048.
#define RDIM 4
#define IDIM 16
#define NPAIR 64
#define NPTS 2048
#define THREADS 256
#define ROWSB 256                   // rows per block (64 per wave)
#define RBLK (NPTS / ROWSB)         // 8
#define T16 (NPTS / 16)             // 128 col-tiles of 16
#define PSPLIT 4                    // prep parallelism split
#define ONEBF 0x3F80u               // bf16(1.0)

typedef __attribute__((ext_vector_type(8))) short bf16x8;
typedef __attribute__((ext_vector_type(4))) float f32x4;

// fminf chain -> backend can fuse to v_min3_f32; no inline asm.
__device__ __forceinline__ float min3f(float a, float b, float c) {
    return fminf(a, fminf(b, c));
}

__device__ __forceinline__ unsigned int f2bf(float f) {
    union { float f; unsigned int u; } v; v.f = f;
    return (v.u + 0x7FFFu + ((v.u >> 16) & 1u)) >> 16;   // RNE bf16 (low 16 bits)
}
__device__ __forceinline__ float bf2f(unsigned int h) {
    union { unsigned int u; float f; } v; v.u = h << 16; return v.f;
}

__device__ __forceinline__ void make_rot(const float* __restrict__ rotv, int pair,
                                         float& r00, float& r01, float& r02,
                                         float& r10, float& r11, float& r12,
                                         float& r20, float& r21, float& r22) {
    const float ax = rotv[pair * 3 + 0];
    const float ay = rotv[pair * 3 + 1];
    const float az = rotv[pair * 3 + 2];
    float sx, cx, sy, cy, sz, cz;
    sincosf(ax, &sx, &cx);
    sincosf(ay, &sy, &cy);
    sincosf(az, &sz, &cz);
    r00 = cy * cz;                r01 = -cy * sz;               r02 = sy;
    r10 = cx * sz + sx * sy * cz; r11 = cx * cz - sx * sy * sz; r12 = -sx * cy;
    r20 = sx * sz - cx * sy * cz; r21 = sx * cz + cx * sy * sz; r22 = cx * cy;
}

// B-record (16 B): shorts [bh0,bh1,bh2, bl0,bl1,bl2, n2h, n2l],  b = split(-2v), n2 = |v|^2
__device__ __forceinline__ uint4 brec(float v0, float v1, float v2) {
    const float b0 = -2.0f * v0, b1 = -2.0f * v1, b2 = -2.0f * v2;
    const unsigned int h0 = f2bf(b0), h1 = f2bf(b1), h2 = f2bf(b2);
    const unsigned int l0 = f2bf(b0 - bf2f(h0));
    const unsigned int l1 = f2bf(b1 - bf2f(h1));
    const unsigned int l2 = f2bf(b2 - bf2f(h2));
    const float n2 = v0 * v0 + v1 * v1 + v2 * v2;
    const unsigned int nh = f2bf(n2), nl = f2bf(n2 - bf2f(nh));
    return make_uint4(h0 | (h1 << 16), h2 | (l0 << 16), l1 | (l2 << 16), nh | (nl << 16));
}
// A-record (32 B): half0 = [qh0,qh1,qh2, ql0,ql1,ql2, 1, 0]
//                  half1 = [ql0,ql1,ql2, qh0,qh1,qh2, 0, 1]
// Against B=[rec] on both k-halves: D = (qh+ql).(bh+bl) + n2h + n2l = -2 q.v + |v|^2
__device__ __forceinline__ void arec(float q0, float q1, float q2, uint4& a0, uint4& a1) {
    const unsigned int h0 = f2bf(q0), h1 = f2bf(q1), h2 = f2bf(q2);
    const unsigned int l0 = f2bf(q0 - bf2f(h0));
    const unsigned int l1 = f2bf(q1 - bf2f(h1));
    const unsigned int l2 = f2bf(q2 - bf2f(h2));
    a0 = make_uint4(h0 | (h1 << 16), h2 | (l0 << 16), l1 | (l2 << 16), ONEBF);
    a1 = make_uint4(l0 | (l1 << 16), l2 | (h0 << 16), h1 | (h2 << 16), ONEBF << 16);
}

// K0: build A/B records for both point sets. Grid (80, PSPLIT).
//   x-blocks 0..63: transformed source (per pair) -> Yb, Ya
//   x-blocks 64..79: target (per i)               -> Xb, Xa
__global__ __launch_bounds__(THREADS)
void prep(const float* __restrict__ src, const float* __restrict__ tgt,
          const float* __restrict__ rotv, const float* __restrict__ trav,
          const float* __restrict__ scal,
          uint4* __restrict__ Yb, uint4* __restrict__ Ya,
          uint4* __restrict__ Xb, uint4* __restrict__ Xa)
{
    const int b   = blockIdx.x;
    const int seg = blockIdx.y;
    const int tid = threadIdx.x;
    const int m0  = seg * (NPTS / PSPLIT);
    if (b < NPAIR) {
        const int pair = b;
        float r00, r01, r02, r10, r11, r12, r20, r21, r22;
        make_rot(rotv, pair, r00, r01, r02, r10, r11, r12, r20, r21, r22);
        const float t0 = trav[pair * 3 + 0];
        const float t1 = trav[pair * 3 + 1];
        const float t2 = trav[pair * 3 + 2];
        const float s  = scal[pair];
        const float* __restrict__ srcp = src + (size_t)pair * NPTS * 3;
#pragma unroll
        for (int u = 0; u < NPTS / THREADS / PSPLIT; ++u) {
            const int m = m0 + u * THREADS + tid;
            const float p0 = srcp[m * 3 + 0];
            const float p1 = srcp[m * 3 + 1];
            const float p2 = srcp[m * 3 + 2];
            const float y0 = s * fmaf(r00, p0, fmaf(r01, p1, fmaf(r02, p2, t0)));
            const float y1 = s * fmaf(r10, p0, fmaf(r11, p1, fmaf(r12, p2, t1)));
            const float y2 = s * fmaf(r20, p0, fmaf(r21, p1, fmaf(r22, p2, t2)));
            Yb[(size_t)pair * NPTS + m] = brec(y0, y1, y2);
            uint4 a0, a1;
            arec(y0, y1, y2, a0, a1);
            Ya[((size_t)pair * NPTS + m) * 2 + 0] = a0;
            Ya[((size_t)pair * NPTS + m) * 2 + 1] = a1;
        }
    } else {
        const int i = b - NPAIR;
        const float* __restrict__ tgtp = tgt + (size_t)i * NPTS * 3;
#pragma unroll
        for (int u = 0; u < NPTS / THREADS / PSPLIT; ++u) {
            const int m = m0 + u * THREADS + tid;
            const float x0 = tgtp[m * 3 + 0];
            const float x1 = tgtp[m * 3 + 1];
            const float x2 = tgtp[m * 3 + 2];
            Xb[(size_t)i * NPTS + m] = brec(x0, x1, x2);
            uint4 a0, a1;
            arec(x0, x1, x2, a0, a1);
            Xa[((size_t)i * NPTS + m) * 2 + 0] = a0;
            Xa[((size_t)i * NPTS + m) * 2 + 1] = a1;
        }
    }
}

// K1: per (pair, rowblock, pass). Each wave owns 64 rows x all 2048 cols.
// mfma_f32_16x16x32_bf16 with zero-padded A (k-groups 2,3 = 0) and broadcast B
// (all k-groups read the same 8-short record): D = -2 q.v + |v|^2 exactly as before,
// but accumulators are 4 regs/MFMA -> total live set ~70 VGPRs, no AGPR pressure.
// A-frags + tail q come straight from global (L2-resident) -> no sA.
// Endgame: shfl_xor butterfly over the 16 column-class lanes -> no LDS transpose.
// LDS = 32768 (sB) + 1024 (rowmin) + 16 -> 4 blocks/CU; grid 1024 = 256 CU x 4.
__global__ __launch_bounds__(THREADS, 4)
void chamfer_main(const uint4* __restrict__ Yb, const uint4* __restrict__ Ya,
                  const uint4* __restrict__ Xb, const uint4* __restrict__ Xa,
                  float* __restrict__ out, const float czero)
{
    __shared__ alignas(16) unsigned char smem[32768];  // sB: 2048 recs x 16 B
    __shared__ float rowmin[ROWSB];
    __shared__ float wsum[4];
    unsigned short* sB = (unsigned short*)smem;        // [2048][8] shorts

    const int pair  = blockIdx.x;
    const int rb    = blockIdx.y;
    const int passB = blockIdx.z;  // 0: rows=target, cols=transformed; 1: swapped
    const int i     = pair & (IDIM - 1);
    const int tid   = threadIdx.x;
    const int lane  = tid & 63;
    const int w     = tid >> 6;
    const int c15   = lane & 15;   // column within tile / class
    const int hi    = lane >> 4;   // k-group 0..3; also row-subgroup in D

    const uint4* __restrict__ gB = (passB == 0) ? (Yb + (size_t)pair * NPTS)
                                                : (Xb + (size_t)i * NPTS);
    const uint4* __restrict__ gA = (passB == 0)
        ? (Xa + ((size_t)i * NPTS + rb * ROWSB) * 2)
        : (Ya + ((size_t)pair * NPTS + rb * ROWSB) * 2);
    const char* gAb = (const char*)gA;                 // 256 rows x 32 B records

    // ---- stage sB: 2048 x 16 B (8 uint4/thread) ----
#pragma unroll
    for (int j = 0; j < 8; ++j)
        ((uint4*)sB)[j * THREADS + tid] = gB[j * THREADS + tid];

    // ---- A fragments from global: wave w rows [w*64, w*64+64), 4 row-tiles of 16.
    // Virtual K=32 row = [record(16 shorts) | zeros]: k-group hi<2 loads half hi, else 0.
    const bf16x8 zero8 = {0, 0, 0, 0, 0, 0, 0, 0};
    bf16x8 af[4];
#pragma unroll
    for (int rt = 0; rt < 4; ++rt) {
        const int row = w * 64 + rt * 16 + c15;
        af[rt] = (hi < 2) ? *(const bf16x8*)(gAb + row * 32 + hi * 16) : zero8;
    }

    // Runtime-opaque zero C operand (4 regs).
    f32x4 zero4;
    zero4[0] = czero; zero4[1] = czero; zero4[2] = czero; zero4[3] = czero;

    float mn[4][4];
#pragma unroll
    for (int rt = 0; rt < 4; ++rt)
#pragma unroll
        for (int j = 0; j < 4; ++j) mn[rt][j] = 3.4e38f;

    __syncthreads();

    // ---- main loop: 128 col-tiles of 16, paired; B record broadcast to all k-groups.
    // Per pair: 2 b128 reads (2-way bank aliasing = free) + 8 MFMA + 16 min3.
#pragma unroll 2
    for (int t = 0; t < T16; t += 2) {
        const bf16x8 bf0 = *(const bf16x8*)&sB[((t + 0) * 16 + c15) * 8];
        const bf16x8 bf1 = *(const bf16x8*)&sB[((t + 1) * 16 + c15) * 8];
#pragma unroll
        for (int rt = 0; rt < 4; ++rt) {
            const f32x4 d0 = __builtin_amdgcn_mfma_f32_16x16x32_bf16(af[rt], bf0, zero4, 0, 0, 0);
            const f32x4 d1 = __builtin_amdgcn_mfma_f32_16x16x32_bf16(af[rt], bf1, zero4, 0, 0, 0);
#pragma unroll
            for (int j = 0; j < 4; ++j)
                mn[rt][j] = min3f(mn[rt][j], d0[j], d1[j]);
        }
    }

    // ---- endgame: D layout col=lane&15, row=(lane>>4)*4+j (m89-verified).
    // Min across the 16 column-class lanes via 4-step shfl_xor butterfly.
#pragma unroll
    for (int rt = 0; rt < 4; ++rt)
#pragma unroll
        for (int j = 0; j < 4; ++j) {
            float v = mn[rt][j];
            v = fminf(v, __shfl_xor(v, 1, 64));
            v = fminf(v, __shfl_xor(v, 2, 64));
            v = fminf(v, __shfl_xor(v, 4, 64));
            v = fminf(v, __shfl_xor(v, 8, 64));
            mn[rt][j] = v;
        }

    // Lane c15==0 of each hi-group publishes its 4 consecutive rows per row-tile.
    if (c15 == 0) {
#pragma unroll
        for (int rt = 0; rt < 4; ++rt) {
            f32x4 v4;
            v4[0] = mn[rt][0]; v4[1] = mn[rt][1];
            v4[2] = mn[rt][2]; v4[3] = mn[rt][3];
            *(f32x4*)&rowmin[w * 64 + rt * 16 + hi * 4] = v4;
        }
    }
    __syncthreads();

    // ---- tail: thread tid = block-row tid; q reconstructed from global A half0.
    const float m = rowmin[tid];
    const unsigned short* ar = (const unsigned short*)(gAb + tid * 32);
    const float q0 = bf2f(ar[0]) + bf2f(ar[3]);
    const float q1 = bf2f(ar[1]) + bf2f(ar[4]);
    const float q2 = bf2f(ar[2]) + bf2f(ar[5]);
    float v = m + q0 * q0 + q1 * q1 + q2 * q2;

#pragma unroll
    for (int off = 32; off > 0; off >>= 1)
        v += __shfl_down(v, off, 64);
    if (lane == 0) wsum[w] = v;
    __syncthreads();
    if (tid == 0) {
        const float tot = wsum[0] + wsum[1] + wsum[2] + wsum[3];
        atomicAdd(&out[pair], tot * (1.0f / NPTS));
    }
}

extern "C" void kernel_launch(void* const* d_in, const int* in_sizes, int n_in,
                              void* d_out, int out_size, void* d_ws, size_t ws_size,
                              hipStream_t stream) {
    const float* src  = (const float*)d_in[0];  // [4,16,2048,3]
    const float* tgt  = (const float*)d_in[1];  // [16,2048,3]
    const float* rotv = (const float*)d_in[2];  // [4,16,3]
    const float* trav = (const float*)d_in[3];  // [4,16,3]
    const float* scal = (const float*)d_in[4];  // [4,16]
    float* out = (float*)d_out;                 // [4,16]

    // ws: Yb 2 MB | Ya 4 MB | Xb 0.5 MB | Xa 1 MB  = 7.5 MB
    char* ws = (char*)d_ws;
    uint4* Yb = (uint4*)ws;
    uint4* Ya = (uint4*)(ws + (size_t)NPAIR * NPTS * 16);
    uint4* Xb = (uint4*)(ws + (size_t)NPAIR * NPTS * 48);
    uint4* Xa = (uint4*)(ws + (size_t)NPAIR * NPTS * 48 + (size_t)IDIM * NPTS * 16);

    hipMemsetAsync(out, 0, NPAIR * sizeof(float), stream);

    dim3 pgrid(NPAIR + IDIM, PSPLIT);
    prep<<<pgrid, THREADS, 0, stream>>>(src, tgt, rotv, trav, scal, Yb, Ya, Xb, Xa);

    dim3 grid(NPAIR, RBLK, 2);
    chamfer_main<<<grid, THREADS, 0, stream>>>(Yb, Ya, Xb, Xa, out, 0.0f);
}

// Round 6
// 85.117 us; speedup vs baseline: 1.2394x; 1.2394x over previous
//
#include <hip/hip_runtime.h>
#include <math.h>

// Problem constants: R=4, I=16, N=2048.
#define RDIM 4
#define IDIM 16
#define NPAIR 64
#define NPTS 2048
#define THREADS 256
#define ROWSB 256                   // rows per block (64 per wave)
#define RBLK (NPTS / ROWSB)         // 8
#define TILES (NPTS / 32)           // 64 col-tiles of 32
#define PSPLIT 4                    // prep parallelism split
#define ONEBF 0x3F80u               // bf16(1.0)

typedef __attribute__((ext_vector_type(8))) short bf16x8;
typedef __attribute__((ext_vector_type(16))) float f32x16;
typedef __attribute__((ext_vector_type(4))) float f32x4;

// fminf chain -> backend can fuse to v_min3_f32; no inline asm.
__device__ __forceinline__ float min3f(float a, float b, float c) {
    return fminf(a, fminf(b, c));
}

__device__ __forceinline__ unsigned int f2bf(float f) {
    union { float f; unsigned int u; } v; v.f = f;
    return (v.u + 0x7FFFu + ((v.u >> 16) & 1u)) >> 16;   // RNE bf16 (low 16 bits)
}
__device__ __forceinline__ float bf2f(unsigned int h) {
    union { unsigned int u; float f; } v; v.u = h << 16; return v.f;
}

__device__ __forceinline__ void make_rot(const float* __restrict__ rotv, int pair,
                                         float& r00, float& r01, float& r02,
                                         float& r10, float& r11, float& r12,
                                         float& r20, float& r21, float& r22) {
    const float ax = rotv[pair * 3 + 0];
    const float ay = rotv[pair * 3 + 1];
    const float az = rotv[pair * 3 + 2];
    float sx, cx, sy, cy, sz, cz;
    sincosf(ax, &sx, &cx);
    sincosf(ay, &sy, &cy);
    sincosf(az, &sz, &cz);
    r00 = cy * cz;                r01 = -cy * sz;               r02 = sy;
    r10 = cx * sz + sx * sy * cz; r11 = cx * cz - sx * sy * sz; r12 = -sx * cy;
    r20 = sx * sz - cx * sy * cz; r21 = sx * cz + cx * sy * sz; r22 = cx * cy;
}

// B-record (16 B): shorts [bh0,bh1,bh2, bl0,bl1,bl2, n2h, n2l],  b = split(-2v), n2 = |v|^2
__device__ __forceinline__ uint4 brec(float v0, float v1, float v2) {
    const float b0 = -2.0f * v0, b1 = -2.0f * v1, b2 = -2.0f * v2;
    const unsigned int h0 = f2bf(b0), h1 = f2bf(b1), h2 = f2bf(b2);
    const unsigned int l0 = f2bf(b0 - bf2f(h0));
    const unsigned int l1 = f2bf(b1 - bf2f(h1));
    const unsigned int l2 = f2bf(b2 - bf2f(h2));
    const float n2 = v0 * v0 + v1 * v1 + v2 * v2;
    const unsigned int nh = f2bf(n2), nl = f2bf(n2 - bf2f(nh));
    return make_uint4(h0 | (h1 << 16), h2 | (l0 << 16), l1 | (l2 << 16), nh | (nl << 16));
}
// A-record (32 B): half0 = [qh0,qh1,qh2, ql0,ql1,ql2, 1, 0]
//                  half1 = [ql0,ql1,ql2, qh0,qh1,qh2, 0, 1]
// K=16 across both halves vs broadcast B=[rec|rec]:
// D = (qh+ql).(bh+bl) + n2h + n2l = -2 q.v + |v|^2   (exact to ~1e-5)
__device__ __forceinline__ void arec(float q0, float q1, float q2, uint4& a0, uint4& a1) {
    const unsigned int h0 = f2bf(q0), h1 = f2bf(q1), h2 = f2bf(q2);
    const unsigned int l0 = f2bf(q0 - bf2f(h0));
    const unsigned int l1 = f2bf(q1 - bf2f(h1));
    const unsigned int l2 = f2bf(q2 - bf2f(h2));
    a0 = make_uint4(h0 | (h1 << 16), h2 | (l0 << 16), l1 | (l2 << 16), ONEBF);
    a1 = make_uint4(l0 | (l1 << 16), l2 | (h0 << 16), h1 | (h2 << 16), ONEBF << 16);
}

// K0: build A/B records for both point sets. Grid (80, PSPLIT).
//   x-blocks 0..63: transformed source (per pair) -> Yb, Ya
//   x-blocks 64..79: target (per i)               -> Xb, Xa
// Block (0,0) also zeroes the output (replaces the hipMemsetAsync dispatch).
__global__ __launch_bounds__(THREADS)
void prep(const float* __restrict__ src, const float* __restrict__ tgt,
          const float* __restrict__ rotv, const float* __restrict__ trav,
          const float* __restrict__ scal,
          uint4* __restrict__ Yb, uint4* __restrict__ Ya,
          uint4* __restrict__ Xb, uint4* __restrict__ Xa,
          float* __restrict__ out)
{
    const int b   = blockIdx.x;
    const int seg = blockIdx.y;
    const int tid = threadIdx.x;
    if (b == 0 && seg == 0 && tid < NPAIR) out[tid] = 0.0f;
    const int m0  = seg * (NPTS / PSPLIT);
    if (b < NPAIR) {
        const int pair = b;
        float r00, r01, r02, r10, r11, r12, r20, r21, r22;
        make_rot(rotv, pair, r00, r01, r02, r10, r11, r12, r20, r21, r22);
        const float t0 = trav[pair * 3 + 0];
        const float t1 = trav[pair * 3 + 1];
        const float t2 = trav[pair * 3 + 2];
        const float s  = scal[pair];
        const float* __restrict__ srcp = src + (size_t)pair * NPTS * 3;
#pragma unroll
        for (int u = 0; u < NPTS / THREADS / PSPLIT; ++u) {
            const int m = m0 + u * THREADS + tid;
            const float p0 = srcp[m * 3 + 0];
            const float p1 = srcp[m * 3 + 1];
            const float p2 = srcp[m * 3 + 2];
            const float y0 = s * fmaf(r00, p0, fmaf(r01, p1, fmaf(r02, p2, t0)));
            const float y1 = s * fmaf(r10, p0, fmaf(r11, p1, fmaf(r12, p2, t1)));
            const float y2 = s * fmaf(r20, p0, fmaf(r21, p1, fmaf(r22, p2, t2)));
            Yb[(size_t)pair * NPTS + m] = brec(y0, y1, y2);
            uint4 a0, a1;
            arec(y0, y1, y2, a0, a1);
            Ya[((size_t)pair * NPTS + m) * 2 + 0] = a0;
            Ya[((size_t)pair * NPTS + m) * 2 + 1] = a1;
        }
    } else {
        const int i = b - NPAIR;
        const float* __restrict__ tgtp = tgt + (size_t)i * NPTS * 3;
#pragma unroll
        for (int u = 0; u < NPTS / THREADS / PSPLIT; ++u) {
            const int m = m0 + u * THREADS + tid;
            const float x0 = tgtp[m * 3 + 0];
            const float x1 = tgtp[m * 3 + 1];
            const float x2 = tgtp[m * 3 + 2];
            Xb[(size_t)i * NPTS + m] = brec(x0, x1, x2);
            uint4 a0, a1;
            arec(x0, x1, x2, a0, a1);
            Xa[((size_t)i * NPTS + m) * 2 + 0] = a0;
            Xa[((size_t)i * NPTS + m) * 2 + 1] = a1;
        }
    }
}

// K1: per (pair, rowblock, pass). Each wave owns 64 rows (2 row-tiles of 32) x 2048 cols.
// 32x32x16 MFMA (fewest MFMAs: 128/wave). 2-deep software pipeline: four rotating
// f32x16 dest sets; each iteration issues rt0 MFMAs, folds PREVIOUS iter's rt1
// (VALU overlaps matrix pipe), issues rt1, folds current rt0. Breaks the
// MFMA->min3->MFMA dest-reuse serialization that stalled R3-R5.
// Live set ~148 VGPRs -> __launch_bounds__(256,3) (cap ~170, no AGPR pressure).
// A-frags + tail q from global (L2-resident); shfl_xor butterfly endgame (no LDS scratch).
__global__ __launch_bounds__(THREADS, 3)
void chamfer_main(const uint4* __restrict__ Yb, const uint4* __restrict__ Ya,
                  const uint4* __restrict__ Xb, const uint4* __restrict__ Xa,
                  float* __restrict__ out, const float czero)
{
    __shared__ alignas(16) unsigned char smem[32768];  // sB: 2048 recs x 16 B
    __shared__ float rowmin[ROWSB];
    __shared__ float wsum[4];
    unsigned short* sB = (unsigned short*)smem;        // [2048][8] shorts

    const int pair  = blockIdx.x;
    const int rb    = blockIdx.y;
    const int passB = blockIdx.z;  // 0: rows=target, cols=transformed; 1: swapped
    const int i     = pair & (IDIM - 1);
    const int tid   = threadIdx.x;
    const int lane  = tid & 63;
    const int w     = tid >> 6;
    const int c31   = lane & 31;   // column within 32-tile
    const int h     = lane >> 5;   // K-half / row-subgroup select

    const uint4* __restrict__ gB = (passB == 0) ? (Yb + (size_t)pair * NPTS)
                                                : (Xb + (size_t)i * NPTS);
    const uint4* __restrict__ gA = (passB == 0)
        ? (Xa + ((size_t)i * NPTS + rb * ROWSB) * 2)
        : (Ya + ((size_t)pair * NPTS + rb * ROWSB) * 2);
    const char* gAb = (const char*)gA;                 // 256 rows x 32 B records

    // ---- stage sB: 2048 x 16 B (8 uint4/thread) ----
#pragma unroll
    for (int j = 0; j < 8; ++j)
        ((uint4*)sB)[j * THREADS + tid] = gB[j * THREADS + tid];

    // ---- A fragments from global: wave w rows [w*64, w*64+64), 2 row-tiles of 32.
    // Lane holds half h (8 shorts) of row (base + c31): K=16 across the two lane-halves.
    const bf16x8 af0 = *(const bf16x8*)(gAb + (w * 64 + c31) * 32 + h * 16);
    const bf16x8 af1 = *(const bf16x8*)(gAb + (w * 64 + 32 + c31) * 32 + h * 16);

    // Runtime-opaque zero C operand (16 regs, resident, never re-materialized).
    f32x16 czv;
#pragma unroll
    for (int j = 0; j < 16; ++j) czv[j] = czero;

    float mn0[16], mn1[16];
#pragma unroll
    for (int j = 0; j < 16; ++j) { mn0[j] = 3.4e38f; mn1[j] = 3.4e38f; }

    __syncthreads();

    // ---- pipelined main loop: 64 col-tiles in pairs (32 iterations) ----
    // prologue (tiles 0,1)
    bf16x8 bfA = *(const bf16x8*)&sB[(0 * 32 + c31) * 8];
    bf16x8 bfB = *(const bf16x8*)&sB[(1 * 32 + c31) * 8];
    f32x16 a0  = __builtin_amdgcn_mfma_f32_32x32x16_bf16(af0, bfA, czv, 0, 0, 0);
    f32x16 b0  = __builtin_amdgcn_mfma_f32_32x32x16_bf16(af0, bfB, czv, 0, 0, 0);
    f32x16 pa1 = __builtin_amdgcn_mfma_f32_32x32x16_bf16(af1, bfA, czv, 0, 0, 0);
    f32x16 pb1 = __builtin_amdgcn_mfma_f32_32x32x16_bf16(af1, bfB, czv, 0, 0, 0);
#pragma unroll
    for (int j = 0; j < 16; ++j)
        mn0[j] = min3f(mn0[j], a0[j], b0[j]);

    for (int t = 2; t < TILES; t += 2) {
        bfA = *(const bf16x8*)&sB[((t + 0) * 32 + c31) * 8];
        bfB = *(const bf16x8*)&sB[((t + 1) * 32 + c31) * 8];
        a0 = __builtin_amdgcn_mfma_f32_32x32x16_bf16(af0, bfA, czv, 0, 0, 0);
        b0 = __builtin_amdgcn_mfma_f32_32x32x16_bf16(af0, bfB, czv, 0, 0, 0);
        // fold PREVIOUS iteration's rt1 while this iteration's rt0 MFMAs run
#pragma unroll
        for (int j = 0; j < 16; ++j)
            mn1[j] = min3f(mn1[j], pa1[j], pb1[j]);
        pa1 = __builtin_amdgcn_mfma_f32_32x32x16_bf16(af1, bfA, czv, 0, 0, 0);
        pb1 = __builtin_amdgcn_mfma_f32_32x32x16_bf16(af1, bfB, czv, 0, 0, 0);
        // fold current rt0 while rt1 MFMAs run
#pragma unroll
        for (int j = 0; j < 16; ++j)
            mn0[j] = min3f(mn0[j], a0[j], b0[j]);
    }
    // epilogue: last rt1
#pragma unroll
    for (int j = 0; j < 16; ++j)
        mn1[j] = min3f(mn1[j], pa1[j], pb1[j]);

    // ---- endgame: D layout (m74/m101): col = lane&31, row = (j&3)+8*(j>>2)+4*h.
    // Min across the 32 column-lanes: 5-step shfl_xor butterfly (bits 0..4 only,
    // stays within each h-half).
#pragma unroll
    for (int j = 0; j < 16; ++j) {
        float v0 = mn0[j], v1 = mn1[j];
        v0 = fminf(v0, __shfl_xor(v0, 1, 64));
        v1 = fminf(v1, __shfl_xor(v1, 1, 64));
        v0 = fminf(v0, __shfl_xor(v0, 2, 64));
        v1 = fminf(v1, __shfl_xor(v1, 2, 64));
        v0 = fminf(v0, __shfl_xor(v0, 4, 64));
        v1 = fminf(v1, __shfl_xor(v1, 4, 64));
        v0 = fminf(v0, __shfl_xor(v0, 8, 64));
        v1 = fminf(v1, __shfl_xor(v1, 8, 64));
        v0 = fminf(v0, __shfl_xor(v0, 16, 64));
        v1 = fminf(v1, __shfl_xor(v1, 16, 64));
        mn0[j] = v0; mn1[j] = v1;
    }

    // Lanes 0 (h=0) and 32 (h=1) publish: quad g -> rows base + 8g + 4h + {0..3}.
    if (c31 == 0) {
#pragma unroll
        for (int g = 0; g < 4; ++g) {
            f32x4 v4, u4;
            v4[0] = mn0[g * 4 + 0]; v4[1] = mn0[g * 4 + 1];
            v4[2] = mn0[g * 4 + 2]; v4[3] = mn0[g * 4 + 3];
            u4[0] = mn1[g * 4 + 0]; u4[1] = mn1[g * 4 + 1];
            u4[2] = mn1[g * 4 + 2]; u4[3] = mn1[g * 4 + 3];
            *(f32x4*)&rowmin[w * 64 + 8 * g + 4 * h] = v4;
            *(f32x4*)&rowmin[w * 64 + 32 + 8 * g + 4 * h] = u4;
        }
    }
    __syncthreads();

    // ---- tail: thread tid = block-row tid; q reconstructed from global A half0.
    const float m = rowmin[tid];
    const unsigned short* ar = (const unsigned short*)(gAb + tid * 32);
    const float q0 = bf2f(ar[0]) + bf2f(ar[3]);
    const float q1 = bf2f(ar[1]) + bf2f(ar[4]);
    const float q2 = bf2f(ar[2]) + bf2f(ar[5]);
    float v = m + q0 * q0 + q1 * q1 + q2 * q2;

#pragma unroll
    for (int off = 32; off > 0; off >>= 1)
        v += __shfl_down(v, off, 64);
    if (lane == 0) wsum[w] = v;
    __syncthreads();
    if (tid == 0) {
        const float tot = wsum[0] + wsum[1] + wsum[2] + wsum[3];
        atomicAdd(&out[pair], tot * (1.0f / NPTS));
    }
}

extern "C" void kernel_launch(void* const* d_in, const int* in_sizes, int n_in,
                              void* d_out, int out_size, void* d_ws, size_t ws_size,
                              hipStream_t stream) {
    const float* src  = (const float*)d_in[0];  // [4,16,2048,3]
    const float* tgt  = (const float*)d_in[1];  // [16,2048,3]
    const float* rotv = (const float*)d_in[2];  // [4,16,3]
    const float* trav = (const float*)d_in[3];  // [4,16,3]
    const float* scal = (const float*)d_in[4];  // [4,16]
    float* out = (float*)d_out;                 // [4,16]

    // ws: Yb 2 MB | Ya 4 MB | Xb 0.5 MB | Xa 1 MB  = 7.5 MB
    char* ws = (char*)d_ws;
    uint4* Yb = (uint4*)ws;
    uint4* Ya = (uint4*)(ws + (size_t)NPAIR * NPTS * 16);
    uint4* Xb = (uint4*)(ws + (size_t)NPAIR * NPTS * 48);
    uint4* Xa = (uint4*)(ws + (size_t)NPAIR * NPTS * 48 + (size_t)IDIM * NPTS * 16);

    dim3 pgrid(NPAIR + IDIM, PSPLIT);
    prep<<<pgrid, THREADS, 0, stream>>>(src, tgt, rotv, trav, scal, Yb, Ya, Xb, Xa, out);

    dim3 grid(NPAIR, RBLK, 2);
    chamfer_main<<<grid, THREADS, 0, stream>>>(Yb, Ya, Xb, Xa, out, 0.0f);
}